// Round 10
// baseline (219.458 us; speedup 1.0000x reference)
//
#include <hip/hip_runtime.h>

// Boundary_binaryLoss: 15x15 binary morphology boundary mask + masked NLL mean.
// B=32, C=2, H=480, W=864. logits [B,C,H,W] f32, labels [B,H,W] i32 in {0,1,255}.
//
// valid(b,h,w) = (label != 255) && (clipped 15x15 window has a px with
//   np_label==0 (label 0 or 255) AND a px with np_label==255 (label 1))
// loss = -sum(valid ? logits[b,label,h,w] : 0) / max(#valid, 1)
//
// R1..R9: atomics(66); sunk prefetch(66); lds-DMA(65); barrier-free scalar
//     (65); spill(91); fat fused R6(63, 292MB L1-path @4.6TB/s); TH32
//     starved(103); block-coop(69); R6+XCD swizzle(64, FETCH 78MB).
// R10: register-walk SEG=3: bytes 190MB (worked) BUT loop-carried state
//     spilled (WRITE 5.8MB, VGPR 64) and 2560 waves -> 2.6 TB/s: 72us.
// MODEL (fits all 10 points): dur ~= L1-path bytes / min(waves*~1.05GB/s,
//     4.6TB/s). R6 sat at the 4.6 wall with fat bytes; R10 cut bytes but
//     fell off the rate curve. Optimum = knee: ~4k waves, min bytes,
//     spill-free FLAT body.
// R11: TH=16 single-seg waves (halo 30/16=1.875x): 99+106=205MB.
//     3840 1-wave blocks (15/CU -> fully resident at VGPR<=128), flat
//     R6 body: 30-row fused fold -> ONE u64/col (60 bits, v-fold max bit
//     58<64), u64 h-OR shuffles, logits as two sequential 8-row half-tiles
//     (named float4[8] pairs, peak 64 VGPR, no loop, no dbuf).
//     Predict: main 48-56us, WRITE ~60KB (spill tripwire), FETCH 85-100MB,
//     occ>=40%. If main >=60 spill-free: model out of levers -> wall.

namespace {
constexpr int B_ = 32;
constexpr int H_ = 480;
constexpr int W_ = 864;
constexpr int HW = H_ * W_;
constexpr int R_ = 7;
constexpr int TH_ = 16;                   // output rows per wave
constexpr int LH = TH_ + 2 * R_;          // 30 label rows
constexpr int SW = 216;                   // output cols per strip
constexpr int NSX = W_ / SW;              // 4
constexpr int NSY = H_ / TH_;             // 30
constexpr int NBLK = B_ * NSX * NSY;      // 3840 single-wave blocks (%8==0)
} // namespace

typedef unsigned long long u64;

__device__ __forceinline__ u64 shfl_up64(u64 x, int d) {
  return __shfl_up(x, d, 64);
}
__device__ __forceinline__ u64 shfl_dn64(u64 x, int d) {
  return __shfl_down(x, d, 64);
}

extern "C" __global__ __launch_bounds__(64, 4)
void boundary_loss_main(const float* __restrict__ logits,
                        const int* __restrict__ labels,
                        double2* __restrict__ partials)
{
  const int lane = threadIdx.x;             // one wave per block
  const int bid = blockIdx.x;
  // XCD swizzle: XCD k owns lb in [480k, 480k+480) = 4 whole images;
  // consecutive lb = vertically adjacent segments (14 shared halo rows
  // stay XCD-local).
  const int lb = (bid & 7) * (NBLK / 8) + (bid >> 3);
  const int img = lb / (NSX * NSY);         // /120
  const int r = lb - img * (NSX * NSY);
  const int strip = r / NSY;                // 0..3
  const int seg = r - strip * NSY;          // 0..29
  const int gr0 = seg * TH_;                // first output row

  const int cb0 = strip * SW - 8 + 4 * lane;          // lane's 4-col base
  const bool colinb = (cb0 >= 0) && (cb0 + 3 < W_);   // W%4==0: all-or-none
  const int cbc = colinb ? cb0 : (cb0 < 0 ? 0 : W_ - 4);
  const bool labok = colinb && (lane < 58);           // 232 halo cols
  const bool outl = (lane >= 2) && (lane < 56);       // 54 lanes x 4 = 216

  const int* __restrict__ lab = labels + img * HW + cbc;
  const float* __restrict__ lg = logits + (size_t)(2 * img) * HW;
  const float* pg = lg + (size_t)gr0 * W_ + cb0;      // deref'd only if outl

  // ---- phase 1: FUSED label load+fold, 30x int4 (~1KB/wave requests).
  // f[j]: 2 bits/label row in ONE u64 (60 bits): bit0 np==0 (label 0/255),
  // bit1 np==255 (label 1). cp[j]: 2 bits/output row (bit0 chan, bit1 ign).
  u64 f0 = 0, f1 = 0, f2 = 0, f3 = 0;
  unsigned cp0 = 0, cp1 = 0, cp2 = 0, cp3 = 0;
#pragma unroll
  for (int a = 0; a < LH; ++a) {
    int gr = gr0 - R_ + a;
    gr = gr < 0 ? 0 : (gr >= H_ ? H_ - 1 : gr);       // clamped; masked below
    const int4 v = *(const int4*)(lab + gr * W_);
    const unsigned e1x = (v.x == 1), e1y = (v.y == 1),
                   e1z = (v.z == 1), e1w = (v.w == 1);
    f0 |= (u64)(1u + e1x) << (2 * a);
    f1 |= (u64)(1u + e1y) << (2 * a);
    f2 |= (u64)(1u + e1z) << (2 * a);
    f3 |= (u64)(1u + e1w) << (2 * a);
    if (a >= R_ && a < R_ + TH_) {
      const int sh = 2 * (a - R_);
      cp0 |= (e1x | ((unsigned)(v.x == 255) << 1)) << sh;
      cp1 |= (e1y | ((unsigned)(v.y == 255) << 1)) << sh;
      cp2 |= (e1z | ((unsigned)(v.z == 255) << 1)) << sh;
      cp3 |= (e1w | ((unsigned)(v.w == 255) << 1)) << sh;
    }
  }
  // clip: OOB image rows / OOB lane columns contribute nothing
  {
    const int tv = gr0 == 0 ? R_ : 0;                   // invalid top rows
    const int hi = LH < (H_ + R_ - gr0) ? LH : (H_ + R_ - gr0);
    u64 rm = (hi - tv >= 32) ? ((((1ull << (2 * (hi - tv) - 32)) - 1ull) << 32)
                                | 0xFFFFFFFFull)
                             : ((1ull << (2 * (hi - tv))) - 1ull);
    rm <<= 2 * tv;
    if (!colinb) rm = 0;
    f0 &= rm; f1 &= rm; f2 &= rm; f3 &= rm;
  }

  // ---- phase 2: issue logits half-tile 0 (rows gr0..gr0+7), latency hides
  //      under the h-OR + v-fold VALU block ----
  float4 a0[8], a1[8];
  if (outl) {
#pragma unroll
    for (int o = 0; o < 8; ++o) {
      a0[o] = *(const float4*)(pg + (size_t)o * W_);
      a1[o] = *(const float4*)(pg + (size_t)o * W_ + HW);
    }
  }

  // ---- phase 3: horizontal 15-OR, exact per column over 4-col lanes ----
  // col 4l+0: sfx3(l-2)|all(l-1..l+1)     col 4l+1: sfx2|core|pfx1(l+2)
  // col 4l+2: sfx1|core|pfx2(l+2)         col 4l+3: all(l-1..l+1)|pfx3(l+2)
  // shuffle garbage only reaches lanes outside [2,56) -> never consumed.
  const u64 allf = f0 | f1 | f2 | f3;
  const u64 s2 = f2 | f3, s3 = f1 | s2;
  const u64 p2 = f0 | f1, p3 = p2 | f2;
  const u64 core = shfl_up64(allf, 1) | allf | shfl_dn64(allf, 1);
  u64 w0 = core | shfl_up64(s3, 2);
  u64 w1 = core | shfl_up64(s2, 2) | shfl_dn64(f0, 2);
  u64 w2 = core | shfl_up64(f3, 2) | shfl_dn64(p2, 2);
  u64 w3 = core | shfl_dn64(p3, 2);

  // ---- phase 4: vertical 15-OR (bit 2o = OR label rows o..o+14, o=0..15;
  //      max source bit 2*15+28 = 58 < 64) ----
  w0 |= w0 >> 2;  w0 |= w0 >> 4;  w0 |= w0 >> 8;  w0 |= w0 >> 14;
  w1 |= w1 >> 2;  w1 |= w1 >> 4;  w1 |= w1 >> 8;  w1 |= w1 >> 14;
  w2 |= w2 >> 2;  w2 |= w2 >> 4;  w2 |= w2 >> 8;  w2 |= w2 >> 14;
  w3 |= w3 >> 2;  w3 |= w3 >> 4;  w3 |= w3 >> 8;  w3 |= w3 >> 14;

  double lsum = 0.0;
  unsigned lcnt = 0;

  // ---- phase 5: consume half 0 / issue+consume half 1 (named buffers,
  //      sequential -- peak live one 64-VGPR logit set, no spill) ----
  if (outl) {
#pragma unroll
    for (int o = 0; o < 8; ++o) {
      const unsigned b0 = (unsigned)(w0 >> (2 * o)) & 3u;
      const unsigned b1 = (unsigned)(w1 >> (2 * o)) & 3u;
      const unsigned b2 = (unsigned)(w2 >> (2 * o)) & 3u;
      const unsigned b3 = (unsigned)(w3 >> (2 * o)) & 3u;
      const unsigned q0 = (cp0 >> (2 * o)) & 3u;
      const unsigned q1 = (cp1 >> (2 * o)) & 3u;
      const unsigned q2 = (cp2 >> (2 * o)) & 3u;
      const unsigned q3 = (cp3 >> (2 * o)) & 3u;
      const float4 a = a0[o], c = a1[o];
      const bool k0 = (b0 == 3u) && !(q0 & 2u);
      const bool k1 = (b1 == 3u) && !(q1 & 2u);
      const bool k2 = (b2 == 3u) && !(q2 & 2u);
      const bool k3 = (b3 == 3u) && !(q3 & 2u);
      lsum += k0 ? (double)((q0 & 1u) ? c.x : a.x) : 0.0;
      lsum += k1 ? (double)((q1 & 1u) ? c.y : a.y) : 0.0;
      lsum += k2 ? (double)((q2 & 1u) ? c.z : a.z) : 0.0;
      lsum += k3 ? (double)((q3 & 1u) ? c.w : a.w) : 0.0;
      lcnt += (unsigned)k0 + k1 + k2 + k3;
    }
  }
  float4 b0v[8], b1v[8];
  if (outl) {
    const float* p_ = pg + (size_t)8 * W_;
#pragma unroll
    for (int o = 0; o < 8; ++o) {
      b0v[o] = *(const float4*)(p_ + (size_t)o * W_);
      b1v[o] = *(const float4*)(p_ + (size_t)o * W_ + HW);
    }
#pragma unroll
    for (int o = 0; o < 8; ++o) {
      const int ro = 8 + o;
      const unsigned b0 = (unsigned)(w0 >> (2 * ro)) & 3u;
      const unsigned b1 = (unsigned)(w1 >> (2 * ro)) & 3u;
      const unsigned b2 = (unsigned)(w2 >> (2 * ro)) & 3u;
      const unsigned b3 = (unsigned)(w3 >> (2 * ro)) & 3u;
      const unsigned q0 = (cp0 >> (2 * ro)) & 3u;
      const unsigned q1 = (cp1 >> (2 * ro)) & 3u;
      const unsigned q2 = (cp2 >> (2 * ro)) & 3u;
      const unsigned q3 = (cp3 >> (2 * ro)) & 3u;
      const float4 a = b0v[o], c = b1v[o];
      const bool k0 = (b0 == 3u) && !(q0 & 2u);
      const bool k1 = (b1 == 3u) && !(q1 & 2u);
      const bool k2 = (b2 == 3u) && !(q2 & 2u);
      const bool k3 = (b3 == 3u) && !(q3 & 2u);
      lsum += k0 ? (double)((q0 & 1u) ? c.x : a.x) : 0.0;
      lsum += k1 ? (double)((q1 & 1u) ? c.y : a.y) : 0.0;
      lsum += k2 ? (double)((q2 & 1u) ? c.z : a.z) : 0.0;
      lsum += k3 ? (double)((q3 & 1u) ? c.w : a.w) : 0.0;
      lcnt += (unsigned)k0 + k1 + k2 + k3;
    }
  }

  // ---- wave reduction -> one double2 per block (no LDS, no barrier) ----
#pragma unroll
  for (int off = 32; off > 0; off >>= 1) {
    lsum += __shfl_down(lsum, off, 64);
    lcnt += __shfl_down(lcnt, off, 64);
  }
  if (lane == 0) partials[bid] = make_double2(lsum, (double)lcnt);
}

extern "C" __global__ __launch_bounds__(1024)
void boundary_loss_final(const double2* __restrict__ partials,
                         float* __restrict__ out)
{
  __shared__ double red_s[16];
  __shared__ double red_c[16];
  const int tid = threadIdx.x;
  double s = 0.0, c = 0.0;
  for (int i = tid; i < NBLK; i += 1024) {
    const double2 p = partials[i];
    s += p.x;
    c += p.y;
  }
#pragma unroll
  for (int off = 32; off > 0; off >>= 1) {
    s += __shfl_down(s, off, 64);
    c += __shfl_down(c, off, 64);
  }
  const int wave = tid >> 6;
  if ((tid & 63) == 0) { red_s[wave] = s; red_c[wave] = c; }
  __syncthreads();
  if (tid == 0) {
    double ts = 0.0, tc = 0.0;
#pragma unroll
    for (int i = 0; i < 16; ++i) { ts += red_s[i]; tc += red_c[i]; }
    if (tc < 1.0) tc = 1.0;
    out[0] = (float)(-ts / tc);
  }
}

extern "C" void kernel_launch(void* const* d_in, const int* in_sizes, int n_in,
                              void* d_out, int out_size, void* d_ws, size_t ws_size,
                              hipStream_t stream)
{
  const float* logits = (const float*)d_in[0];
  const int* labels = (const int*)d_in[1];
  float* out = (float*)d_out;
  double2* partials = (double2*)d_ws;  // NBLK*16 B = 61,440 B; every slot
                                       // written by main -> no init needed.

  boundary_loss_main<<<dim3(NBLK), 64, 0, stream>>>(logits, labels, partials);
  boundary_loss_final<<<1, 1024, 0, stream>>>(partials, out);
}

// Round 11
// 194.136 us; speedup vs baseline: 1.1304x; 1.1304x over previous
//
#include <hip/hip_runtime.h>

// Boundary_binaryLoss: 15x15 binary morphology boundary mask + masked NLL mean.
// B=32, C=2, H=480, W=864. logits [B,C,H,W] f32, labels [B,H,W] i32 in {0,1,255}.
//
// valid(b,h,w) = (label != 255) && (clipped 15x15 window has a px with
//   np_label==0 (label 0 or 255) AND a px with np_label==255 (label 1))
// loss = -sum(valid ? logits[b,label,h,w] : 0) / max(#valid, 1)
//
// R1..R9: atomics(66); sunk prefetch(66); lds-DMA(65); barrier-free scalar
//     (65); spill(91); fat fused R6(63 = best, 292MB @4.6TB/s, VGPR 80,
//     launch_bounds(256,2)); TH32 starved(103); block-coop(69); +XCD
//     swizzle(64, FETCH 78MB).
// R10/R11: byte-reduction designs both KILLED BY SPILL: launch_bounds 2nd
//     arg >=4 makes the compiler squeeze to 64 VGPR and spill (R10 WRITE
//     5.8MB; R11 122MB). R11's key datum: 205MB intended + 244MB scratch =
//     449MB moved in 100us = 4.5 TB/s AT ONLY 3840 WAVES -> the ~4.6TB/s
//     rate holds at 3840 waves; the slowdown was purely spill bytes.
//     MODEL STANDS: dur ~= L1-path bytes / 4.5TB/s (waves >= ~3.8k).
// R12: R11 with the spill surgically removed, nothing else:
//     (1) __launch_bounds__(64,2) -- the R6-proven arm, no 64-VGPR squeeze;
//     (2) logits in 4 quarter-tiles (4 rows x 2ch = 32 VGPR each),
//         issue(i+1)/consume(i) pipeline -> peak 2 quarters = 64 VGPR live,
//         total live ~105 <= 128 -> 4 waves/SIMD, all 3840 resident;
//     (3) sched_barrier(0) after each consume: compile-time fence so the
//         scheduler cannot hoist quarter i+2's loads above consume i
//         (the hoist is what blew R11's live set).
//     Predict: main 46-52us, WRITE ~60KB (tripwire), VGPR 100-128,
//     FETCH 85-100MB. If main >=60 spill-free: model out of levers ->
//     restore R9, declare wall.

namespace {
constexpr int B_ = 32;
constexpr int H_ = 480;
constexpr int W_ = 864;
constexpr int HW = H_ * W_;
constexpr int R_ = 7;
constexpr int TH_ = 16;                   // output rows per wave
constexpr int LH = TH_ + 2 * R_;          // 30 label rows
constexpr int SW = 216;                   // output cols per strip
constexpr int NSX = W_ / SW;              // 4
constexpr int NSY = H_ / TH_;             // 30
constexpr int NBLK = B_ * NSX * NSY;      // 3840 single-wave blocks (%8==0)
} // namespace

typedef unsigned long long u64;

__device__ __forceinline__ u64 shfl_up64(u64 x, int d) {
  return __shfl_up(x, d, 64);
}
__device__ __forceinline__ u64 shfl_dn64(u64 x, int d) {
  return __shfl_down(x, d, 64);
}

extern "C" __global__ __launch_bounds__(64, 2)
void boundary_loss_main(const float* __restrict__ logits,
                        const int* __restrict__ labels,
                        double2* __restrict__ partials)
{
  const int lane = threadIdx.x;             // one wave per block
  const int bid = blockIdx.x;
  // XCD swizzle: XCD k owns lb in [480k, 480k+480) = 4 whole images;
  // consecutive lb = vertically adjacent segments (halo rows XCD-local).
  const int lb = (bid & 7) * (NBLK / 8) + (bid >> 3);
  const int img = lb / (NSX * NSY);         // /120
  const int r = lb - img * (NSX * NSY);
  const int strip = r / NSY;                // 0..3
  const int seg = r - strip * NSY;          // 0..29
  const int gr0 = seg * TH_;                // first output row

  const int cb0 = strip * SW - 8 + 4 * lane;          // lane's 4-col base
  const bool colinb = (cb0 >= 0) && (cb0 + 3 < W_);   // W%4==0: all-or-none
  const int cbc = colinb ? cb0 : (cb0 < 0 ? 0 : W_ - 4);
  const bool labok = colinb && (lane < 58);           // 232 halo cols
  const bool outl = (lane >= 2) && (lane < 56);       // 54 lanes x 4 = 216

  const int* __restrict__ lab = labels + img * HW + cbc;
  const float* __restrict__ lg = logits + (size_t)(2 * img) * HW;
  const float* pg = lg + (size_t)gr0 * W_ + cb0;      // deref'd only if outl

  // ---- phase 1: FUSED label load+fold, 30x int4 (~1KB/wave requests).
  // f[j]: 2 bits/label row in ONE u64 (60 bits): bit0 np==0 (label 0/255),
  // bit1 np==255 (label 1). cp[j]: 2 bits/output row (bit0 chan, bit1 ign).
  u64 f0 = 0, f1 = 0, f2 = 0, f3 = 0;
  unsigned cp0 = 0, cp1 = 0, cp2 = 0, cp3 = 0;
#pragma unroll
  for (int a = 0; a < LH; ++a) {
    int gr = gr0 - R_ + a;
    gr = gr < 0 ? 0 : (gr >= H_ ? H_ - 1 : gr);       // clamped; masked below
    const int4 v = *(const int4*)(lab + gr * W_);
    const unsigned e1x = (v.x == 1), e1y = (v.y == 1),
                   e1z = (v.z == 1), e1w = (v.w == 1);
    f0 |= (u64)(1u + e1x) << (2 * a);
    f1 |= (u64)(1u + e1y) << (2 * a);
    f2 |= (u64)(1u + e1z) << (2 * a);
    f3 |= (u64)(1u + e1w) << (2 * a);
    if (a >= R_ && a < R_ + TH_) {
      const int sh = 2 * (a - R_);
      cp0 |= (e1x | ((unsigned)(v.x == 255) << 1)) << sh;
      cp1 |= (e1y | ((unsigned)(v.y == 255) << 1)) << sh;
      cp2 |= (e1z | ((unsigned)(v.z == 255) << 1)) << sh;
      cp3 |= (e1w | ((unsigned)(v.w == 255) << 1)) << sh;
    }
  }
  // clip: OOB image rows / OOB lane columns contribute nothing
  {
    const int tv = gr0 == 0 ? R_ : 0;                   // invalid top rows
    const int hi = LH < (H_ + R_ - gr0) ? LH : (H_ + R_ - gr0);
    u64 rm = (2 * (hi - tv) >= 32)
                 ? ((((1ull << (2 * (hi - tv) - 32)) - 1ull) << 32) | 0xFFFFFFFFull)
                 : ((1ull << (2 * (hi - tv))) - 1ull);
    rm <<= 2 * tv;
    if (!colinb) rm = 0;
    f0 &= rm; f1 &= rm; f2 &= rm; f3 &= rm;
  }

  // ---- logits quarter-tile machinery: 4 rows x 2 ch = 8 float4 = 32 VGPR
  //      per quarter; A/B named buffers, static indexing only ----
  float4 qa0[4], qa1[4], qb0[4], qb1[4];
#define ISSUE(G0, G1, q)                                                    \
  if (outl) {                                                               \
    const float* p_ = pg + (size_t)(4 * (q)) * W_;                          \
    _Pragma("unroll") for (int o = 0; o < 4; ++o) {                         \
      G0[o] = *(const float4*)(p_ + (size_t)o * W_);                        \
      G1[o] = *(const float4*)(p_ + (size_t)o * W_ + HW);                   \
    }                                                                       \
  }

  // issue Q0 now: latency hides under h-OR + v-fold VALU
  ISSUE(qa0, qa1, 0)

  // ---- phase 3: horizontal 15-OR, exact per column over 4-col lanes ----
  // col 4l+0: sfx3(l-2)|all(l-1..l+1)     col 4l+1: sfx2|core|pfx1(l+2)
  // col 4l+2: sfx1|core|pfx2(l+2)         col 4l+3: all(l-1..l+1)|pfx3(l+2)
  // shuffle garbage only reaches lanes outside [2,56) -> never consumed.
  const u64 allf = f0 | f1 | f2 | f3;
  const u64 s2 = f2 | f3, s3 = f1 | s2;
  const u64 p2 = f0 | f1, p3 = p2 | f2;
  const u64 core = shfl_up64(allf, 1) | allf | shfl_dn64(allf, 1);
  u64 w0 = core | shfl_up64(s3, 2);
  u64 w1 = core | shfl_up64(s2, 2) | shfl_dn64(f0, 2);
  u64 w2 = core | shfl_up64(f3, 2) | shfl_dn64(p2, 2);
  u64 w3 = core | shfl_dn64(p3, 2);

  // ---- phase 4: vertical 15-OR (bit 2o = OR label rows o..o+14, o=0..15;
  //      max source bit 2*15+28 = 58 < 64) ----
  w0 |= w0 >> 2;  w0 |= w0 >> 4;  w0 |= w0 >> 8;  w0 |= w0 >> 14;
  w1 |= w1 >> 2;  w1 |= w1 >> 4;  w1 |= w1 >> 8;  w1 |= w1 >> 14;
  w2 |= w2 >> 2;  w2 |= w2 >> 4;  w2 |= w2 >> 8;  w2 |= w2 >> 14;
  w3 |= w3 >> 2;  w3 |= w3 >> 4;  w3 |= w3 >> 8;  w3 |= w3 >> 14;

  double lsum = 0.0;
  unsigned lcnt = 0;
#define CONSUME(G0, G1, q)                                                  \
  if (outl) {                                                               \
    _Pragma("unroll") for (int o = 0; o < 4; ++o) {                         \
      const int ro = 4 * (q) + o;                                           \
      const unsigned b0 = (unsigned)(w0 >> (2 * ro)) & 3u;                  \
      const unsigned b1 = (unsigned)(w1 >> (2 * ro)) & 3u;                  \
      const unsigned b2 = (unsigned)(w2 >> (2 * ro)) & 3u;                  \
      const unsigned b3 = (unsigned)(w3 >> (2 * ro)) & 3u;                  \
      const unsigned q0 = (cp0 >> (2 * ro)) & 3u;                           \
      const unsigned q1 = (cp1 >> (2 * ro)) & 3u;                           \
      const unsigned q2 = (cp2 >> (2 * ro)) & 3u;                           \
      const unsigned q3 = (cp3 >> (2 * ro)) & 3u;                           \
      const float4 a = G0[o], c = G1[o];                                    \
      const bool k0 = (b0 == 3u) && !(q0 & 2u);                             \
      const bool k1 = (b1 == 3u) && !(q1 & 2u);                             \
      const bool k2 = (b2 == 3u) && !(q2 & 2u);                             \
      const bool k3 = (b3 == 3u) && !(q3 & 2u);                             \
      lsum += k0 ? (double)((q0 & 1u) ? c.x : a.x) : 0.0;                   \
      lsum += k1 ? (double)((q1 & 1u) ? c.y : a.y) : 0.0;                   \
      lsum += k2 ? (double)((q2 & 1u) ? c.z : a.z) : 0.0;                   \
      lsum += k3 ? (double)((q3 & 1u) ? c.w : a.w) : 0.0;                   \
      lcnt += (unsigned)k0 + k1 + k2 + k3;                                  \
    }                                                                       \
  }

  // ---- phase 5: 4-quarter software pipeline; sched_barrier(0) fences
  //      prevent the scheduler hoisting issue(i+2) above consume(i), so at
  //      most 2 quarters (64 VGPR) of logits are ever live ----
  ISSUE(qb0, qb1, 1)
  CONSUME(qa0, qa1, 0)
  __builtin_amdgcn_sched_barrier(0);
  ISSUE(qa0, qa1, 2)
  CONSUME(qb0, qb1, 1)
  __builtin_amdgcn_sched_barrier(0);
  ISSUE(qb0, qb1, 3)
  CONSUME(qa0, qa1, 2)
  __builtin_amdgcn_sched_barrier(0);
  CONSUME(qb0, qb1, 3)
#undef ISSUE
#undef CONSUME

  // ---- wave reduction -> one double2 per block (no LDS, no barrier) ----
#pragma unroll
  for (int off = 32; off > 0; off >>= 1) {
    lsum += __shfl_down(lsum, off, 64);
    lcnt += __shfl_down(lcnt, off, 64);
  }
  if (lane == 0) partials[bid] = make_double2(lsum, (double)lcnt);
}

extern "C" __global__ __launch_bounds__(1024)
void boundary_loss_final(const double2* __restrict__ partials,
                         float* __restrict__ out)
{
  __shared__ double red_s[16];
  __shared__ double red_c[16];
  const int tid = threadIdx.x;
  double s = 0.0, c = 0.0;
  for (int i = tid; i < NBLK; i += 1024) {
    const double2 p = partials[i];
    s += p.x;
    c += p.y;
  }
#pragma unroll
  for (int off = 32; off > 0; off >>= 1) {
    s += __shfl_down(s, off, 64);
    c += __shfl_down(c, off, 64);
  }
  const int wave = tid >> 6;
  if ((tid & 63) == 0) { red_s[wave] = s; red_c[wave] = c; }
  __syncthreads();
  if (tid == 0) {
    double ts = 0.0, tc = 0.0;
#pragma unroll
    for (int i = 0; i < 16; ++i) { ts += red_s[i]; tc += red_c[i]; }
    if (tc < 1.0) tc = 1.0;
    out[0] = (float)(-ts / tc);
  }
}

extern "C" void kernel_launch(void* const* d_in, const int* in_sizes, int n_in,
                              void* d_out, int out_size, void* d_ws, size_t ws_size,
                              hipStream_t stream)
{
  const float* logits = (const float*)d_in[0];
  const int* labels = (const int*)d_in[1];
  float* out = (float*)d_out;
  double2* partials = (double2*)d_ws;  // NBLK*16 B = 61,440 B; every slot
                                       // written by main -> no init needed.

  boundary_loss_main<<<dim3(NBLK), 64, 0, stream>>>(logits, labels, partials);
  boundary_loss_final<<<1, 1024, 0, stream>>>(partials, out);
}